// Round 1
// baseline (1086.855 us; speedup 1.0000x reference)
//
#include <hip/hip_runtime.h>
#include <math.h>

// Problem constants
#define Bb 2
#define Ss 576
#define Ff 16
#define Dd 512
#define Hh 8
#define Cc 64
#define HC 512
#define Mrows (Bb * Ss * Ff)   // 18432

// ---------------------------------------------------------------------------
// GEMM: C[M,512] = A[M,512] @ W[512,512] (+bias). 128x128 block tile, 8x8
// microtile per thread (split as rows {4i..4i+3, 64+4i..} for conflict-free
// b128 LDS frag reads). K-chunk = 32, A staged transposed (k-major) in LDS.
// ---------------------------------------------------------------------------
__device__ __forceinline__ void gemm_tile(const float* __restrict__ A,
                                          const float* __restrict__ W,
                                          const float* __restrict__ bias,
                                          float* __restrict__ Cmat,
                                          int mt, int nt)
{
    __shared__ float As[32][132];   // As[k][m], stride 132 -> 16B-aligned f4 reads
    __shared__ float Bs[32][132];   // Bs[k][n]
    const int t  = threadIdx.x;
    const int ti = t & 15, tj = t >> 4;
    const int m0 = mt * 128, n0 = nt * 128;

    float acc[8][8];
#pragma unroll
    for (int r = 0; r < 8; ++r)
#pragma unroll
        for (int c = 0; c < 8; ++c) acc[r][c] = 0.f;

    for (int k0 = 0; k0 < 512; k0 += 32) {
        // stage A tile (transposed into k-major)
#pragma unroll
        for (int i = 0; i < 4; ++i) {
            int idx = t + i * 256;
            int k4 = idx & 7, m = idx >> 3;
            float4 av = *(const float4*)&A[(size_t)(m0 + m) * 512 + k0 + k4 * 4];
            As[k4 * 4 + 0][m] = av.x;
            As[k4 * 4 + 1][m] = av.y;
            As[k4 * 4 + 2][m] = av.z;
            As[k4 * 4 + 3][m] = av.w;
        }
        // stage W tile (already k-major)
#pragma unroll
        for (int i = 0; i < 4; ++i) {
            int idx = t + i * 256;
            int n4 = idx & 31, kk = idx >> 5;
            *(float4*)&Bs[kk][n4 * 4] =
                *(const float4*)&W[(size_t)(k0 + kk) * 512 + n0 + n4 * 4];
        }
        __syncthreads();
#pragma unroll 8
        for (int kk = 0; kk < 32; ++kk) {
            float4 a0 = *(const float4*)&As[kk][4 * ti];
            float4 a1 = *(const float4*)&As[kk][64 + 4 * ti];
            float4 b0 = *(const float4*)&Bs[kk][4 * tj];
            float4 b1 = *(const float4*)&Bs[kk][64 + 4 * tj];
            float ar[8] = {a0.x, a0.y, a0.z, a0.w, a1.x, a1.y, a1.z, a1.w};
            float br[8] = {b0.x, b0.y, b0.z, b0.w, b1.x, b1.y, b1.z, b1.w};
#pragma unroll
            for (int r = 0; r < 8; ++r)
#pragma unroll
                for (int c = 0; c < 8; ++c)
                    acc[r][c] = fmaf(ar[r], br[c], acc[r][c]);
        }
        __syncthreads();
    }
#pragma unroll
    for (int r = 0; r < 8; ++r) {
        int m = m0 + ((r < 4) ? (4 * ti + r) : (64 + 4 * ti + (r - 4)));
#pragma unroll
        for (int half = 0; half < 2; ++half) {
            int n = n0 + (half ? (64 + 4 * tj) : (4 * tj));
            float4 o;
            o.x = acc[r][half * 4 + 0];
            o.y = acc[r][half * 4 + 1];
            o.z = acc[r][half * 4 + 2];
            o.w = acc[r][half * 4 + 3];
            if (bias) {
                o.x += bias[n + 0]; o.y += bias[n + 1];
                o.z += bias[n + 2]; o.w += bias[n + 3];
            }
            *(float4*)&Cmat[(size_t)m * 512 + n] = o;
        }
    }
}

__global__ __launch_bounds__(256) void gemm_qkv_kernel(
    const float* __restrict__ x,
    const float* __restrict__ Wq, const float* __restrict__ Wk,
    const float* __restrict__ Wv,
    float* __restrict__ q, float* __restrict__ k, float* __restrict__ v)
{
    const int which = blockIdx.z;
    const float* W = (which == 0) ? Wq : (which == 1) ? Wk : Wv;
    float* C = (which == 0) ? q : (which == 1) ? k : v;
    gemm_tile(x, W, nullptr, C, blockIdx.x, blockIdx.y);
}

__global__ __launch_bounds__(256) void gemm_out_kernel(
    const float* __restrict__ res, const float* __restrict__ Wout,
    const float* __restrict__ bout, float* __restrict__ out)
{
    gemm_tile(res, Wout, bout, out, blockIdx.x, blockIdx.y);
}

// ---------------------------------------------------------------------------
// Fused attention. One block = 64 queries of one (b, head, frame-role).
//   mode 0 (blocks 0..143):  resq — q frame 0 vs gathered frames (df=9 -> 81
//                            key tiles), frame list from drop_mask.
//   mode 1 (blocks 144..):   ress — per-frame self-attention (9 key tiles).
// Flash-style online softmax, 64-key tiles. S/P tile aliases the K-tile LDS
// (phases barrier-separated) to stay under 64 KB -> 3 blocks/CU.
// ---------------------------------------------------------------------------
__global__ __launch_bounds__(256) void attn_kernel(
    const float* __restrict__ q, const float* __restrict__ k,
    const float* __restrict__ v, const int* __restrict__ dm,
    float* __restrict__ res)
{
    __shared__ float Qs[64][68];    // c-major: Qs[c][query], pre-scaled
    __shared__ float KSs[64][68];   // phase A: K c-major [c][key]; phase B: St[key][query]
    __shared__ float Vs[64][68];    // row-major [key][c]
    __shared__ float m_s[64], l_s[64], al_s[64];
    __shared__ int   skey[64];      // per-key global row base
    __shared__ int   fl[16];
    __shared__ int   df_s;

    const int t = threadIdx.x;
    const int bi = blockIdx.x;

    int b, h, qt, qframe, mode;
    if (bi < Bb * Hh * 9) {                     // 144 resq blocks (long poles first)
        mode = 0;
        b = bi / (Hh * 9);
        int r = bi % (Hh * 9);
        h = r / 9; qt = r % 9;
        qframe = 0;
    } else {
        mode = 1;
        int idx = bi - Bb * Hh * 9;
        b = idx / ((Ff - 1) * Hh * 9);          // 1080 per batch
        int r = idx % ((Ff - 1) * Hh * 9);
        int fi = r / (Hh * 9);
        int r2 = r % (Hh * 9);
        h = r2 / 9; qt = r2 % 9;
        qframe = 1 + fi;
    }

    if (t == 0) {
        if (mode == 0) {
            int n = 0;
            fl[n++] = 0; fl[n++] = 1;
            for (int j = 0; j < Ff - 2; ++j)
                if (dm[b * (Ff - 2) + j] == 0) fl[n++] = 2 + j;
            df_s = n;
        } else {
            df_s = 1;
        }
    }
    if (t < 64) { m_s[t] = -INFINITY; l_s[t] = 0.f; }

    // load + scale Q tile (transpose to c-major)
    {
        const int c = t & 63;
        const int w = t >> 6;
#pragma unroll
        for (int i = 0; i < 16; ++i) {
            int sl = w + i * 4;
            int s = qt * 64 + sl;
            float val = q[(size_t)((b * Ss + s) * Ff + qframe) * HC + h * Cc + c];
            Qs[c][sl] = val * 0.125f;   // 1/sqrt(C)
        }
    }
    __syncthreads();

    const int df  = df_s;
    const int nkt = (mode == 0) ? (Ss * df) / 64 : 9;   // S*df is always /64

    const int ti = t & 15, tj = t >> 4;
    float o_acc[4][4];
#pragma unroll
    for (int r = 0; r < 4; ++r)
#pragma unroll
        for (int c = 0; c < 4; ++c) o_acc[r][c] = 0.f;

    for (int kt = 0; kt < nkt; ++kt) {
        // key -> global row base mapping
        if (t < 64) {
            int kkg = kt * 64 + t;
            int s, frame;
            if (mode == 0) { s = kkg / df; frame = fl[kkg - s * df]; }
            else           { s = kkg;     frame = qframe; }
            skey[t] = ((b * Ss + s) * Ff + frame) * HC + h * Cc;
        }
        __syncthreads();   // also fences prev-iteration PV reads of KSs/Vs

        // stage K (c-major) and V (row-major)
        {
            const int c = t & 63;
            const int w = t >> 6;
#pragma unroll
            for (int i = 0; i < 16; ++i) {
                int kk = w + i * 4;
                KSs[c][kk] = k[(size_t)skey[kk] + c];
                Vs[kk][c]  = v[(size_t)skey[kk] + c];
            }
        }
        __syncthreads();

        // S = Q K^T  (4x4 microtile: queries 4*ti.., keys 4*tj..)
        float s_acc[4][4];
#pragma unroll
        for (int r = 0; r < 4; ++r)
#pragma unroll
            for (int c = 0; c < 4; ++c) s_acc[r][c] = 0.f;
#pragma unroll 8
        for (int c = 0; c < 64; ++c) {
            float4 qa = *(const float4*)&Qs[c][4 * ti];
            float4 kb = *(const float4*)&KSs[c][4 * tj];
            float ar[4] = {qa.x, qa.y, qa.z, qa.w};
            float br[4] = {kb.x, kb.y, kb.z, kb.w};
#pragma unroll
            for (int r = 0; r < 4; ++r)
#pragma unroll
                for (int c2 = 0; c2 < 4; ++c2)
                    s_acc[r][c2] = fmaf(ar[r], br[c2], s_acc[r][c2]);
        }
        __syncthreads();   // all reads of K done; KSs can be reused as St

        // write St[key][query] (transposed -> b128 reads in PV)
#pragma unroll
        for (int kk = 0; kk < 4; ++kk) {
            float4 w4 = make_float4(s_acc[0][kk], s_acc[1][kk],
                                    s_acc[2][kk], s_acc[3][kk]);
            *(float4*)&KSs[4 * tj + kk][4 * ti] = w4;
        }
        __syncthreads();

        // online-softmax stats: quad (4 threads) per query row
        {
            const int r = t >> 2, p = t & 3;
            float mx = -INFINITY;
#pragma unroll
            for (int e = 0; e < 16; ++e) mx = fmaxf(mx, KSs[p * 16 + e][r]);
            mx = fmaxf(mx, __shfl_xor(mx, 1));
            mx = fmaxf(mx, __shfl_xor(mx, 2));
            float m_old = m_s[r];
            float m_new = fmaxf(m_old, mx);
            float sum = 0.f;
#pragma unroll
            for (int e = 0; e < 16; ++e) {
                float pv = __expf(KSs[p * 16 + e][r] - m_new);
                KSs[p * 16 + e][r] = pv;
                sum += pv;
            }
            sum += __shfl_xor(sum, 1);
            sum += __shfl_xor(sum, 2);
            if (p == 0) {
                float alpha = (m_old == -INFINITY) ? 0.f : __expf(m_old - m_new);
                al_s[r] = alpha;
                l_s[r]  = l_s[r] * alpha + sum;
                m_s[r]  = m_new;
            }
        }
        __syncthreads();

        // O = O*alpha + P V  (queries 4*ti.., channels 4*tj..)
        {
            float alpha[4];
#pragma unroll
            for (int rr = 0; rr < 4; ++rr) alpha[rr] = al_s[4 * ti + rr];
#pragma unroll
            for (int rr = 0; rr < 4; ++rr)
#pragma unroll
                for (int cc = 0; cc < 4; ++cc) o_acc[rr][cc] *= alpha[rr];
#pragma unroll 8
            for (int kk = 0; kk < 64; ++kk) {
                float4 pf = *(const float4*)&KSs[kk][4 * ti];
                float4 vf = *(const float4*)&Vs[kk][4 * tj];
                float pr[4] = {pf.x, pf.y, pf.z, pf.w};
                float vr[4] = {vf.x, vf.y, vf.z, vf.w};
#pragma unroll
                for (int rr = 0; rr < 4; ++rr)
#pragma unroll
                    for (int cc = 0; cc < 4; ++cc)
                        o_acc[rr][cc] = fmaf(pr[rr], vr[cc], o_acc[rr][cc]);
            }
        }
        // loop-top barrier protects KSs/Vs reuse
    }

    // epilogue: normalize and store into res[b, s, qframe, h*C + c]
#pragma unroll
    for (int rr = 0; rr < 4; ++rr) {
        int sl = 4 * ti + rr;
        float inv = 1.f / l_s[sl];
        int s = qt * 64 + sl;
        float4 o = make_float4(o_acc[rr][0] * inv, o_acc[rr][1] * inv,
                               o_acc[rr][2] * inv, o_acc[rr][3] * inv);
        *(float4*)&res[(size_t)((b * Ss + s) * Ff + qframe) * HC + h * Cc + 4 * tj] = o;
    }
}

// ---------------------------------------------------------------------------
extern "C" void kernel_launch(void* const* d_in, const int* in_sizes, int n_in,
                              void* d_out, int out_size, void* d_ws, size_t ws_size,
                              hipStream_t stream)
{
    (void)in_sizes; (void)n_in; (void)out_size; (void)ws_size;
    const float* x    = (const float*)d_in[0];
    const int*   dmsk = (const int*)  d_in[1];
    const float* Wq   = (const float*)d_in[2];
    const float* Wk   = (const float*)d_in[3];
    const float* Wv   = (const float*)d_in[4];
    const float* Wout = (const float*)d_in[5];
    const float* bout = (const float*)d_in[6];
    float* out = (float*)d_out;

    // workspace: q, k, v, res — each 18432x512 fp32 (37.75 MB), total 151 MB
    float* q   = (float*)d_ws;
    float* kk  = q  + (size_t)Mrows * HC;
    float* vv  = kk + (size_t)Mrows * HC;
    float* res = vv + (size_t)Mrows * HC;

    gemm_qkv_kernel<<<dim3(144, 4, 3), 256, 0, stream>>>(x, Wq, Wk, Wv, q, kk, vv);
    attn_kernel<<<dim3(144 + 2160), 256, 0, stream>>>(q, kk, vv, dmsk, res);
    gemm_out_kernel<<<dim3(144, 4), 256, 0, stream>>>(res, Wout, bout, out);
}

// Round 2
// 350.317 us; speedup vs baseline: 3.1025x; 3.1025x over previous
//
#include <hip/hip_runtime.h>
#include <math.h>

#define Bb 2
#define Ss 576
#define Ff 16
#define Hh 8
#define Cc 64
#define HC 512
#define Mrows (Bb * Ss * Ff)   // 18432

typedef __bf16 bf16x8 __attribute__((ext_vector_type(8)));
typedef float  f32x4  __attribute__((ext_vector_type(4)));
typedef unsigned short u16;
typedef unsigned int   u32;

__device__ __forceinline__ u16 f2bf(float f) {
    u32 u = __float_as_uint(f);
    u32 r = (u + 0x7FFFu + ((u >> 16) & 1u)) >> 16;   // RNE
    return (u16)r;
}

// ---------------------------------------------------------------------------
// Convert x (fp32) -> bf16, elementwise.  9437184 el / 2048 per block = 4608.
// ---------------------------------------------------------------------------
__global__ __launch_bounds__(256) void convert_x_kernel(
    const float* __restrict__ x, u16* __restrict__ xb)
{
    size_t idx = ((size_t)blockIdx.x * 256 + threadIdx.x) * 8;
    f32x4 a = *(const f32x4*)&x[idx];
    f32x4 b = *(const f32x4*)&x[idx + 4];
    union { u16 s[8]; uint4 v; } u;
#pragma unroll
    for (int j = 0; j < 4; ++j) u.s[j] = f2bf(a[j]);
#pragma unroll
    for (int j = 0; j < 4; ++j) u.s[4 + j] = f2bf(b[j]);
    *(uint4*)&xb[idx] = u.v;
}

// ---------------------------------------------------------------------------
// Transpose+convert the 4 weight matrices: Wt[n][k] = W[k][n], bf16.
// grid (8,8,4): 64x64 tiles, z = matrix id.
// ---------------------------------------------------------------------------
__global__ __launch_bounds__(256) void convert_w_kernel(
    const float* __restrict__ W0, const float* __restrict__ W1,
    const float* __restrict__ W2, const float* __restrict__ W3,
    u16* __restrict__ Wt)
{
    __shared__ float Ts[64][65];
    const int mz = blockIdx.z;
    const float* W = (mz == 0) ? W0 : (mz == 1) ? W1 : (mz == 2) ? W2 : W3;
    u16* Wo = Wt + (size_t)mz * 512 * 512;
    const int k0 = blockIdx.x * 64, n0 = blockIdx.y * 64;
    const int t = threadIdx.x;
#pragma unroll
    for (int p = 0; p < 4; ++p) {
        int idx = t + p * 256;
        int row = idx >> 4, cg = idx & 15;
        *(float4*)&Ts[row][cg * 4] =
            *(const float4*)&W[(size_t)(k0 + row) * 512 + n0 + cg * 4];
    }
    __syncthreads();
#pragma unroll
    for (int p = 0; p < 2; ++p) {
        int idx = t + p * 256;
        int row = idx >> 3, cg = idx & 7;   // row = local n
        union { u16 s[8]; uint4 v; } u;
#pragma unroll
        for (int j = 0; j < 8; ++j) u.s[j] = f2bf(Ts[cg * 8 + j][row]);
        *(uint4*)&Wo[(size_t)(n0 + row) * 512 + k0 + cg * 8] = u.v;
    }
}

// ---------------------------------------------------------------------------
// bf16 MFMA GEMM: C[M,512] = A[M,512] @ Wt^T.  128x128 tile, BK=32,
// 4 waves, each 64x64 quadrant = 4x4 grid of 16x16x32 MFMAs.
// ---------------------------------------------------------------------------
template <int OUT_BF16>
__device__ __forceinline__ void gemm_body(
    const u16* __restrict__ A, const u16* __restrict__ Wt,
    const float* __restrict__ bias, void* __restrict__ Cout, int mt, int nt)
{
    __shared__ u16 As[128 * 40];   // [m][k] pitch 40 el (80B) -> minimal banking
    __shared__ u16 Bs[128 * 40];   // [n][k]
    const int t = threadIdx.x;
    const int w = t >> 6, L = t & 63;
    const int m0 = mt * 128, n0 = nt * 128;
    const int wm = (w >> 1) * 64, wn = (w & 1) * 64;

    f32x4 acc[4][4];
#pragma unroll
    for (int i = 0; i < 4; ++i)
#pragma unroll
        for (int j = 0; j < 4; ++j) acc[i][j] = (f32x4){0.f, 0.f, 0.f, 0.f};

    for (int k0 = 0; k0 < 512; k0 += 32) {
#pragma unroll
        for (int p = 0; p < 2; ++p) {
            int idx = t + p * 256;
            int row = idx >> 2, cg = idx & 3;
            *(uint4*)&As[row * 40 + cg * 8] =
                *(const uint4*)&A[(size_t)(m0 + row) * 512 + k0 + cg * 8];
            *(uint4*)&Bs[row * 40 + cg * 8] =
                *(const uint4*)&Wt[(size_t)(n0 + row) * 512 + k0 + cg * 8];
        }
        __syncthreads();
        bf16x8 af[4], bfr[4];
#pragma unroll
        for (int i = 0; i < 4; ++i) {
            af[i]  = *(const bf16x8*)&As[(wm + 16 * i + (L & 15)) * 40 + (L >> 4) * 8];
            bfr[i] = *(const bf16x8*)&Bs[(wn + 16 * i + (L & 15)) * 40 + (L >> 4) * 8];
        }
#pragma unroll
        for (int i = 0; i < 4; ++i)
#pragma unroll
            for (int j = 0; j < 4; ++j)
                acc[i][j] = __builtin_amdgcn_mfma_f32_16x16x32_bf16(
                    af[i], bfr[j], acc[i][j], 0, 0, 0);
        __syncthreads();
    }

#pragma unroll
    for (int i = 0; i < 4; ++i)
#pragma unroll
        for (int j = 0; j < 4; ++j)
#pragma unroll
            for (int r = 0; r < 4; ++r) {
                int row = m0 + wm + 16 * i + (L >> 4) * 4 + r;
                int col = n0 + wn + 16 * j + (L & 15);
                float vv = acc[i][j][r];
                if (OUT_BF16) {
                    float pv = __shfl_xor(vv, 1);
                    if (!(L & 1)) {
                        u32 pk = (u32)f2bf(vv) | ((u32)f2bf(pv) << 16);
                        *(u32*)((u16*)Cout + (size_t)row * 512 + col) = pk;
                    }
                } else {
                    ((float*)Cout)[(size_t)row * 512 + col] = vv + bias[col];
                }
            }
}

__global__ __launch_bounds__(256) void gemm_qkv_kernel(
    const u16* __restrict__ xb, const u16* __restrict__ Wt,
    u16* __restrict__ q, u16* __restrict__ k, u16* __restrict__ v)
{
    const int which = blockIdx.z;
    const u16* W = Wt + (size_t)which * 512 * 512;
    u16* C = (which == 0) ? q : (which == 1) ? k : v;
    gemm_body<1>(xb, W, nullptr, C, blockIdx.x, blockIdx.y);
}

__global__ __launch_bounds__(256) void gemm_out_kernel(
    const u16* __restrict__ res, const u16* __restrict__ Wt3,
    const float* __restrict__ bout, float* __restrict__ out)
{
    gemm_body<0>(res, Wt3, bout, out, blockIdx.x, blockIdx.y);
}

// ---------------------------------------------------------------------------
// Transpose v -> vT[b][f][h][c][s]  (s contiguous) for PV B-operand frags.
// 2304 blocks: one 64(s) x 64(c) tile per (b,f,h,stile).
// ---------------------------------------------------------------------------
__global__ __launch_bounds__(256) void transpose_v_kernel(
    const u16* __restrict__ v, u16* __restrict__ vT)
{
    __shared__ u16 Ts[64 * 72];
    int bid = blockIdx.x;
    const int st = bid % 9; bid /= 9;
    const int h = bid % Hh; bid /= Hh;
    const int f = bid % Ff;
    const int b = bid / Ff;
    const int t = threadIdx.x;
#pragma unroll
    for (int p = 0; p < 2; ++p) {
        int idx = t + p * 256;
        int row = idx >> 3, cg = idx & 7;   // row = local s
        *(uint4*)&Ts[row * 72 + cg * 8] =
            *(const uint4*)&v[(size_t)((b * Ss + st * 64 + row) * Ff + f) * HC + h * Cc + cg * 8];
    }
    __syncthreads();
#pragma unroll
    for (int p = 0; p < 2; ++p) {
        int idx = t + p * 256;
        int c = idx >> 3, sg = idx & 7;
        union { u16 s[8]; uint4 u4; } u;
#pragma unroll
        for (int j = 0; j < 8; ++j) u.s[j] = Ts[(sg * 8 + j) * 72 + c];
        *(uint4*)&vT[((size_t)((b * Ff + f) * Hh + h) * Cc + c) * Ss + st * 64 + sg * 8] = u.u4;
    }
}

// ---------------------------------------------------------------------------
// MFMA flash attention.  Block = 64 queries of one (b,h,role); 4 waves, wave w
// owns queries 16w..16w+15 (softmax state fully in registers).  Key tiles are
// 64 contiguous s of ONE frame (key order is softmax-invariant, so resq's
// gathered frames are visited frame-major).
// ---------------------------------------------------------------------------
__global__ __launch_bounds__(256) void attn_kernel(
    const u16* __restrict__ q, const u16* __restrict__ k,
    const u16* __restrict__ vT, const int* __restrict__ dm,
    u16* __restrict__ res)
{
    __shared__ u16 Qs[64 * 72];    // [q][c]
    __shared__ u16 Ks[64 * 72];    // [key][c]
    __shared__ u16 Vts[64 * 72];   // [c][key]
    __shared__ float Ps[64 * 68];  // P fp32 [q][key]
    __shared__ int fl[16];
    __shared__ int df_s;

    const int t = threadIdx.x;
    const int w = t >> 6, L = t & 63;
    const int bi = blockIdx.x;

    int b, h, qt, qframe, mode;
    if (bi < Bb * Hh * 9) {                 // resq: long poles first
        mode = 0;
        b = bi / (Hh * 9);
        int r = bi % (Hh * 9);
        h = r / 9; qt = r % 9; qframe = 0;
    } else {
        mode = 1;
        int idx = bi - Bb * Hh * 9;
        b = idx / ((Ff - 1) * Hh * 9);
        int r = idx % ((Ff - 1) * Hh * 9);
        int fi = r / (Hh * 9);
        int r2 = r % (Hh * 9);
        h = r2 / 9; qt = r2 % 9; qframe = 1 + fi;
    }

    if (t == 0) {
        if (mode == 0) {
            int n = 0;
            fl[n++] = 0; fl[n++] = 1;
            for (int j = 0; j < Ff - 2; ++j)
                if (dm[b * (Ff - 2) + j] == 0) fl[n++] = 2 + j;
            df_s = n;
        } else df_s = 1;
    }

    // stage Q tile [q][c]
#pragma unroll
    for (int p = 0; p < 2; ++p) {
        int idx = t + p * 256;
        int row = idx >> 3, cg = idx & 7;
        *(uint4*)&Qs[row * 72 + cg * 8] =
            *(const uint4*)&q[(size_t)((b * Ss + qt * 64 + row) * Ff + qframe) * HC + h * Cc + cg * 8];
    }
    __syncthreads();

    const int df  = df_s;
    const int nkt = (mode == 0) ? df * 9 : 9;

    float m_r[4], l_r[4];
#pragma unroll
    for (int r = 0; r < 4; ++r) { m_r[r] = -1e30f; l_r[r] = 0.f; }
    f32x4 o[4];
#pragma unroll
    for (int c = 0; c < 4; ++c) o[c] = (f32x4){0.f, 0.f, 0.f, 0.f};

    for (int kt = 0; kt < nkt; ++kt) {
        int kf, s0;
        if (mode == 0) { int fi = kt / 9; kf = fl[fi]; s0 = (kt - fi * 9) * 64; }
        else           { kf = qframe;     s0 = kt * 64; }

        __syncthreads();   // all waves done reading prev Ks/Vts
#pragma unroll
        for (int p = 0; p < 2; ++p) {
            int idx = t + p * 256;
            int row = idx >> 3, cg = idx & 7;
            *(uint4*)&Ks[row * 72 + cg * 8] =
                *(const uint4*)&k[(size_t)((b * Ss + s0 + row) * Ff + kf) * HC + h * Cc + cg * 8];
            *(uint4*)&Vts[row * 72 + cg * 8] =
                *(const uint4*)&vT[((size_t)((b * Ff + kf) * Hh + h) * Cc + row) * Ss + s0 + cg * 8];
        }
        __syncthreads();

        // S = Q K^T for this wave's 16 queries x 64 keys
        f32x4 s[4];
#pragma unroll
        for (int n = 0; n < 4; ++n) s[n] = (f32x4){0.f, 0.f, 0.f, 0.f};
        bf16x8 aq0 = *(const bf16x8*)&Qs[(16 * w + (L & 15)) * 72 + (L >> 4) * 8];
        bf16x8 aq1 = *(const bf16x8*)&Qs[(16 * w + (L & 15)) * 72 + 32 + (L >> 4) * 8];
#pragma unroll
        for (int n = 0; n < 4; ++n) {
            bf16x8 bk0 = *(const bf16x8*)&Ks[(n * 16 + (L & 15)) * 72 + (L >> 4) * 8];
            bf16x8 bk1 = *(const bf16x8*)&Ks[(n * 16 + (L & 15)) * 72 + 32 + (L >> 4) * 8];
            s[n] = __builtin_amdgcn_mfma_f32_16x16x32_bf16(aq0, bk0, s[n], 0, 0, 0);
            s[n] = __builtin_amdgcn_mfma_f32_16x16x32_bf16(aq1, bk1, s[n], 0, 0, 0);
        }

        // scale + in-register row stats (rows spread over 16-lane groups)
        float mx[4];
#pragma unroll
        for (int r = 0; r < 4; ++r) {
            s[0][r] *= 0.125f; s[1][r] *= 0.125f;
            s[2][r] *= 0.125f; s[3][r] *= 0.125f;
            mx[r] = fmaxf(fmaxf(s[0][r], s[1][r]), fmaxf(s[2][r], s[3][r]));
        }
#pragma unroll
        for (int d = 1; d < 16; d <<= 1)
#pragma unroll
            for (int r = 0; r < 4; ++r) mx[r] = fmaxf(mx[r], __shfl_xor(mx[r], d));

        float al[4], rs[4];
#pragma unroll
        for (int r = 0; r < 4; ++r) {
            float mn = fmaxf(m_r[r], mx[r]);
            al[r] = __expf(m_r[r] - mn);
            m_r[r] = mn;
            float p0 = __expf(s[0][r] - mn);
            float p1 = __expf(s[1][r] - mn);
            float p2 = __expf(s[2][r] - mn);
            float p3 = __expf(s[3][r] - mn);
            s[0][r] = p0; s[1][r] = p1; s[2][r] = p2; s[3][r] = p3;
            rs[r] = (p0 + p1) + (p2 + p3);
        }
#pragma unroll
        for (int d = 1; d < 16; d <<= 1)
#pragma unroll
            for (int r = 0; r < 4; ++r) rs[r] += __shfl_xor(rs[r], d);
#pragma unroll
        for (int r = 0; r < 4; ++r) l_r[r] = l_r[r] * al[r] + rs[r];

        // P -> LDS (fp32, C-layout scatter is conflict-free); own rows only
#pragma unroll
        for (int n = 0; n < 4; ++n)
#pragma unroll
            for (int r = 0; r < 4; ++r)
                Ps[(16 * w + (L >> 4) * 4 + r) * 68 + n * 16 + (L & 15)] = s[n][r];

        // rescale O
#pragma unroll
        for (int c = 0; c < 4; ++c)
#pragma unroll
            for (int r = 0; r < 4; ++r) o[c][r] *= al[r];

        // PV: A-frag from Ps (f32 -> bf16), B-frag from Vts
        bf16x8 pa[2];
#pragma unroll
        for (int kc = 0; kc < 2; ++kc) {
            const float* pp = &Ps[(16 * w + (L & 15)) * 68 + kc * 32 + (L >> 4) * 8];
            union { u16 s8[8]; bf16x8 v; } u;
#pragma unroll
            for (int j = 0; j < 8; ++j) u.s8[j] = f2bf(pp[j]);
            pa[kc] = u.v;
        }
#pragma unroll
        for (int c = 0; c < 4; ++c) {
            bf16x8 bv0 = *(const bf16x8*)&Vts[(c * 16 + (L & 15)) * 72 + (L >> 4) * 8];
            bf16x8 bv1 = *(const bf16x8*)&Vts[(c * 16 + (L & 15)) * 72 + 32 + (L >> 4) * 8];
            o[c] = __builtin_amdgcn_mfma_f32_16x16x32_bf16(pa[0], bv0, o[c], 0, 0, 0);
            o[c] = __builtin_amdgcn_mfma_f32_16x16x32_bf16(pa[1], bv1, o[c], 0, 0, 0);
        }
    }

    // epilogue: normalize, pack 2 bf16, store
#pragma unroll
    for (int c = 0; c < 4; ++c)
#pragma unroll
        for (int r = 0; r < 4; ++r) {
            float val = o[c][r] / l_r[r];
            float pv = __shfl_xor(val, 1);
            if (!(L & 1)) {
                int sq = qt * 64 + 16 * w + (L >> 4) * 4 + r;
                int col = h * Cc + c * 16 + (L & 15);
                u32 pk = (u32)f2bf(val) | ((u32)f2bf(pv) << 16);
                *(u32*)&res[(size_t)((b * Ss + sq) * Ff + qframe) * HC + col] = pk;
            }
        }
}

// ---------------------------------------------------------------------------
extern "C" void kernel_launch(void* const* d_in, const int* in_sizes, int n_in,
                              void* d_out, int out_size, void* d_ws, size_t ws_size,
                              hipStream_t stream)
{
    (void)in_sizes; (void)n_in; (void)out_size; (void)ws_size;
    const float* x    = (const float*)d_in[0];
    const int*   dmsk = (const int*)  d_in[1];
    const float* Wq   = (const float*)d_in[2];
    const float* Wk   = (const float*)d_in[3];
    const float* Wv   = (const float*)d_in[4];
    const float* Wout = (const float*)d_in[5];
    const float* bout = (const float*)d_in[6];
    float* out = (float*)d_out;

    const size_t NE = (size_t)Mrows * HC;   // 9437184
    u16* xb  = (u16*)d_ws;
    u16* q   = xb  + NE;
    u16* kk  = q   + NE;
    u16* vv  = kk  + NE;
    u16* vT  = vv  + NE;
    u16* res = vT  + NE;
    u16* Wt  = res + NE;                    // 4 x 512x512

    convert_x_kernel<<<4608, 256, 0, stream>>>(x, xb);
    convert_w_kernel<<<dim3(8, 8, 4), 256, 0, stream>>>(Wq, Wk, Wv, Wout, Wt);
    gemm_qkv_kernel<<<dim3(144, 4, 3), 256, 0, stream>>>(xb, Wt, q, kk, vv);
    transpose_v_kernel<<<2304, 256, 0, stream>>>(vv, vT);
    attn_kernel<<<2304, 256, 0, stream>>>(q, kk, vT, dmsk, res);
    gemm_out_kernel<<<dim3(144, 4), 256, 0, stream>>>(
        res, Wt + (size_t)3 * 512 * 512, bout, out);
}

// Round 3
// 268.266 us; speedup vs baseline: 4.0514x; 1.3059x over previous
//
#include <hip/hip_runtime.h>
#include <math.h>

#define Bb 2
#define Ss 576
#define Ff 16
#define Hh 8
#define Cc 64
#define HC 512
#define Mrows (Bb * Ss * Ff)   // 18432

typedef __bf16 bf16x8 __attribute__((ext_vector_type(8)));
typedef float  f32x4  __attribute__((ext_vector_type(4)));
typedef unsigned short u16;
typedef unsigned int   u32;

#if __has_builtin(__builtin_amdgcn_exp2f)
#define EXP2(x) __builtin_amdgcn_exp2f(x)
#else
#define EXP2(x) exp2f(x)
#endif

// q pre-scale: 1/sqrt(C) * log2(e), folded into the q GEMM epilogue
#define QSCALE 0.18033688011112042f

__device__ __forceinline__ u16 f2bf(float f) {
    union { __bf16 b; u16 u; } cv;
    cv.b = (__bf16)f;          // hardware RNE convert
    return cv.u;
}

// XOR swizzles: group = 16B chunk of a row. 8-group rows (64 u16) and
// 4-group rows (32 u16). Spreads b128 frag reads over all 8 bank-sets.
__device__ __forceinline__ int swz8(int row, int g) {   // u16 offset
    return row * 64 + (((g ^ (row & 7) ^ (((row >> 3) & 1) << 1)) & 7) << 3);
}
__device__ __forceinline__ int swzg(int row, int g) {
    return row * 32 + (((g ^ (row & 3)) & 3) << 3);
}

// ---------------------------------------------------------------------------
__global__ __launch_bounds__(256) void convert_x_kernel(
    const float* __restrict__ x, u16* __restrict__ xb)
{
    size_t idx = ((size_t)blockIdx.x * 256 + threadIdx.x) * 8;
    f32x4 a = *(const f32x4*)&x[idx];
    f32x4 b = *(const f32x4*)&x[idx + 4];
    union { u16 s[8]; uint4 v; } u;
#pragma unroll
    for (int j = 0; j < 4; ++j) u.s[j] = f2bf(a[j]);
#pragma unroll
    for (int j = 0; j < 4; ++j) u.s[4 + j] = f2bf(b[j]);
    *(uint4*)&xb[idx] = u.v;
}

// ---------------------------------------------------------------------------
__global__ __launch_bounds__(256) void convert_w_kernel(
    const float* __restrict__ W0, const float* __restrict__ W1,
    const float* __restrict__ W2, const float* __restrict__ W3,
    u16* __restrict__ Wt)
{
    __shared__ float Ts[64][65];
    const int mz = blockIdx.z;
    const float* W = (mz == 0) ? W0 : (mz == 1) ? W1 : (mz == 2) ? W2 : W3;
    u16* Wo = Wt + (size_t)mz * 512 * 512;
    const int k0 = blockIdx.x * 64, n0 = blockIdx.y * 64;
    const int t = threadIdx.x;
#pragma unroll
    for (int p = 0; p < 4; ++p) {
        int idx = t + p * 256;
        int row = idx >> 4, cg = idx & 15;
        *(float4*)&Ts[row][cg * 4] =
            *(const float4*)&W[(size_t)(k0 + row) * 512 + n0 + cg * 4];
    }
    __syncthreads();
#pragma unroll
    for (int p = 0; p < 2; ++p) {
        int idx = t + p * 256;
        int row = idx >> 3, cg = idx & 7;   // row = local n
        union { u16 s[8]; uint4 v; } u;
#pragma unroll
        for (int j = 0; j < 8; ++j) u.s[j] = f2bf(Ts[cg * 8 + j][row]);
        *(uint4*)&Wo[(size_t)(n0 + row) * 512 + k0 + cg * 8] = u.v;
    }
}

// ---------------------------------------------------------------------------
// bf16 MFMA GEMM, 128x128 tile, BK=32, swizzled LDS, register prefetch.
// ---------------------------------------------------------------------------
template <int OUT_BF16>
__device__ __forceinline__ void gemm_body(
    const u16* __restrict__ A, const u16* __restrict__ Wt,
    const float* __restrict__ bias, float scale, void* __restrict__ Cout,
    int mt, int nt)
{
    __shared__ u16 As[128 * 32];
    __shared__ u16 Bs[128 * 32];
    const int t = threadIdx.x;
    const int w = t >> 6, L = t & 63;
    const int m0 = mt * 128, n0 = nt * 128;
    const int wm = (w >> 1) * 64, wn = (w & 1) * 64;

    const int srow = t >> 2, scg = t & 3;
    const u16* Ap = A  + (size_t)(m0 + srow) * 512 + scg * 8;
    const u16* Bp = Wt + (size_t)(n0 + srow) * 512 + scg * 8;
    const int lo0 = swzg(srow, scg), lo1 = swzg(srow + 64, scg);

    uint4 ua0 = *(const uint4*)(Ap);
    uint4 ua1 = *(const uint4*)(Ap + 64 * 512);
    uint4 ub0 = *(const uint4*)(Bp);
    uint4 ub1 = *(const uint4*)(Bp + 64 * 512);

    f32x4 acc[4][4];
#pragma unroll
    for (int i = 0; i < 4; ++i)
#pragma unroll
        for (int j = 0; j < 4; ++j) acc[i][j] = (f32x4){0.f, 0.f, 0.f, 0.f};

    for (int k0 = 0; k0 < 512; k0 += 32) {
        __syncthreads();
        *(uint4*)&As[lo0] = ua0;
        *(uint4*)&As[lo1] = ua1;
        *(uint4*)&Bs[lo0] = ub0;
        *(uint4*)&Bs[lo1] = ub1;
        __syncthreads();
        if (k0 < 480) {
            const u16* ap = Ap + k0 + 32;
            const u16* bp = Bp + k0 + 32;
            ua0 = *(const uint4*)(ap);
            ua1 = *(const uint4*)(ap + 64 * 512);
            ub0 = *(const uint4*)(bp);
            ub1 = *(const uint4*)(bp + 64 * 512);
        }
        bf16x8 af[4], bfr[4];
#pragma unroll
        for (int i = 0; i < 4; ++i) {
            af[i]  = *(const bf16x8*)&As[swzg(wm + 16 * i + (L & 15), L >> 4)];
            bfr[i] = *(const bf16x8*)&Bs[swzg(wn + 16 * i + (L & 15), L >> 4)];
        }
#pragma unroll
        for (int i = 0; i < 4; ++i)
#pragma unroll
            for (int j = 0; j < 4; ++j)
                acc[i][j] = __builtin_amdgcn_mfma_f32_16x16x32_bf16(
                    af[i], bfr[j], acc[i][j], 0, 0, 0);
    }

#pragma unroll
    for (int i = 0; i < 4; ++i)
#pragma unroll
        for (int j = 0; j < 4; ++j)
#pragma unroll
            for (int r = 0; r < 4; ++r) {
                int row = m0 + wm + 16 * i + (L >> 4) * 4 + r;
                int col = n0 + wn + 16 * j + (L & 15);
                float vv = acc[i][j][r] * scale;
                if (OUT_BF16) {
                    float pvv = __shfl_xor(vv, 1);
                    if (!(L & 1)) {
                        u32 pk2 = (u32)f2bf(vv) | ((u32)f2bf(pvv) << 16);
                        *(u32*)((u16*)Cout + (size_t)row * 512 + col) = pk2;
                    }
                } else {
                    ((float*)Cout)[(size_t)row * 512 + col] = vv + bias[col];
                }
            }
}

__global__ __launch_bounds__(256) void gemm_qkv_kernel(
    const u16* __restrict__ xb, const u16* __restrict__ Wt,
    u16* __restrict__ q, u16* __restrict__ k, u16* __restrict__ v)
{
    const int which = blockIdx.z;
    const u16* W = Wt + (size_t)which * 512 * 512;
    u16* C = (which == 0) ? q : (which == 1) ? k : v;
    float scale = (which == 0) ? QSCALE : 1.0f;
    gemm_body<1>(xb, W, nullptr, scale, C, blockIdx.x, blockIdx.y);
}

__global__ __launch_bounds__(256) void gemm_out_kernel(
    const u16* __restrict__ res, const u16* __restrict__ Wt3,
    const float* __restrict__ bout, float* __restrict__ out)
{
    gemm_body<0>(res, Wt3, bout, 1.0f, out, blockIdx.x, blockIdx.y);
}

// ---------------------------------------------------------------------------
// Transpose v -> vT[b][f][h][c][s]  (s contiguous).
// ---------------------------------------------------------------------------
__global__ __launch_bounds__(256) void transpose_v_kernel(
    const u16* __restrict__ v, u16* __restrict__ vT)
{
    __shared__ u16 Ts[64 * 72];
    int bid = blockIdx.x;
    const int st = bid % 9; bid /= 9;
    const int h = bid % Hh; bid /= Hh;
    const int f = bid % Ff;
    const int b = bid / Ff;
    const int t = threadIdx.x;
#pragma unroll
    for (int p = 0; p < 2; ++p) {
        int idx = t + p * 256;
        int row = idx >> 3, cg = idx & 7;
        *(uint4*)&Ts[row * 72 + cg * 8] =
            *(const uint4*)&v[(size_t)((b * Ss + st * 64 + row) * Ff + f) * HC + h * Cc + cg * 8];
    }
    __syncthreads();
#pragma unroll
    for (int p = 0; p < 2; ++p) {
        int idx = t + p * 256;
        int c = idx >> 3, sg = idx & 7;
        union { u16 s[8]; uint4 u4; } u;
#pragma unroll
        for (int j = 0; j < 8; ++j) u.s[j] = Ts[(sg * 8 + j) * 72 + c];
        *(uint4*)&vT[((size_t)((b * Ff + f) * Hh + h) * Cc + c) * Ss + st * 64 + sg * 8] = u.u4;
    }
}

// ---------------------------------------------------------------------------
// MFMA flash attention, no-max softmax (P = 2^(q'.k), q' pre-scaled by
// 0.125*log2e in the q GEMM).  Deferred l-reduction, bf16 P in LDS,
// swizzled tiles, register prefetch of next K/V tile.
// ---------------------------------------------------------------------------
__global__ __launch_bounds__(256) void attn_kernel(
    const u16* __restrict__ q, const u16* __restrict__ k,
    const u16* __restrict__ vT, const int* __restrict__ dm,
    u16* __restrict__ res)
{
    __shared__ u16 Qs[64 * 64];    // [q][c]      swizzled
    __shared__ u16 Ks[64 * 64];    // [key][c]    swizzled
    __shared__ u16 Vts[64 * 64];   // [c][key]    swizzled
    __shared__ u16 Ps[64 * 64];    // [q][key]    swizzled, bf16
    __shared__ int fl[16];
    __shared__ int df_s;

    const int t = threadIdx.x;
    const int w = t >> 6, L = t & 63;
    const int bi = blockIdx.x;

    int b, h, qt, qframe, mode;
    if (bi < Bb * Hh * 9) {                 // resq: long poles first
        mode = 0;
        b = bi / (Hh * 9);
        int r = bi % (Hh * 9);
        h = r / 9; qt = r % 9; qframe = 0;
    } else {
        mode = 1;
        int idx = bi - Bb * Hh * 9;
        b = idx / ((Ff - 1) * Hh * 9);
        int r = idx % ((Ff - 1) * Hh * 9);
        int fi = r / (Hh * 9);
        int r2 = r % (Hh * 9);
        h = r2 / 9; qt = r2 % 9; qframe = 1 + fi;
    }

    if (t == 0) {
        if (mode == 0) {
            int n = 0;
            fl[n++] = 0; fl[n++] = 1;
            for (int j = 0; j < Ff - 2; ++j)
                if (dm[b * (Ff - 2) + j] == 0) fl[n++] = 2 + j;
            df_s = n;
        } else df_s = 1;
    }

    const int srow = t >> 3, scg = t & 7;   // staging coords (rows 0..31, +32)

    // stage Q tile [q][c] (swizzled)
#pragma unroll
    for (int p = 0; p < 2; ++p) {
        int row = srow + p * 32;
        *(uint4*)&Qs[swz8(row, scg)] =
            *(const uint4*)&q[(size_t)((b * Ss + qt * 64 + row) * Ff + qframe) * HC + h * Cc + scg * 8];
    }
    __syncthreads();

    const int nkt = (mode == 0) ? df_s * 9 : 9;

    // hoisted Q A-frags (Qs never overwritten)
    bf16x8 aq0 = *(const bf16x8*)&Qs[swz8(16 * w + (L & 15), (L >> 4))];
    bf16x8 aq1 = *(const bf16x8*)&Qs[swz8(16 * w + (L & 15), (L >> 4) + 4)];

    float lsum[4] = {0.f, 0.f, 0.f, 0.f};
    f32x4 o[4];
#pragma unroll
    for (int c = 0; c < 4; ++c) o[c] = (f32x4){0.f, 0.f, 0.f, 0.f};

    uint4 pk0, pk1, pv0, pv1;
    {   // preload tile 0
        int kf = (mode == 0) ? fl[0] : qframe;
        const u16* kpp = k + (size_t)((b * Ss + srow) * Ff + kf) * HC + h * Cc + scg * 8;
        pk0 = *(const uint4*)kpp;
        pk1 = *(const uint4*)(kpp + (size_t)32 * Ff * HC);
        const u16* vpp = vT + ((size_t)((b * Ff + kf) * Hh + h) * Cc + srow) * Ss + scg * 8;
        pv0 = *(const uint4*)vpp;
        pv1 = *(const uint4*)(vpp + (size_t)32 * Ss);
    }

    const int lko0 = swz8(srow, scg), lko1 = swz8(srow + 32, scg);

    for (int kt = 0; kt < nkt; ++kt) {
        __syncthreads();                    // all waves done reading prev tiles
        *(uint4*)&Ks[lko0]  = pk0;
        *(uint4*)&Ks[lko1]  = pk1;
        *(uint4*)&Vts[lko0] = pv0;
        *(uint4*)&Vts[lko1] = pv1;
        __syncthreads();

        if (kt + 1 < nkt) {                 // prefetch next tile into regs
            int kn = kt + 1, kf, s0;
            if (mode == 0) { int fi = kn / 9; kf = fl[fi]; s0 = (kn - fi * 9) * 64; }
            else           { kf = qframe;     s0 = kn * 64; }
            const u16* kpp = k + (size_t)((b * Ss + s0 + srow) * Ff + kf) * HC + h * Cc + scg * 8;
            pk0 = *(const uint4*)kpp;
            pk1 = *(const uint4*)(kpp + (size_t)32 * Ff * HC);
            const u16* vpp = vT + ((size_t)((b * Ff + kf) * Hh + h) * Cc + srow) * Ss + s0 + scg * 8;
            pv0 = *(const uint4*)vpp;
            pv1 = *(const uint4*)(vpp + (size_t)32 * Ss);
        }

        // S = Q K^T  (wave w: its 16 queries x 64 keys)
        f32x4 s[4];
#pragma unroll
        for (int n = 0; n < 4; ++n) s[n] = (f32x4){0.f, 0.f, 0.f, 0.f};
#pragma unroll
        for (int n = 0; n < 4; ++n) {
            bf16x8 bk0 = *(const bf16x8*)&Ks[swz8(n * 16 + (L & 15), (L >> 4))];
            bf16x8 bk1 = *(const bf16x8*)&Ks[swz8(n * 16 + (L & 15), (L >> 4) + 4)];
            s[n] = __builtin_amdgcn_mfma_f32_16x16x32_bf16(aq0, bk0, s[n], 0, 0, 0);
            s[n] = __builtin_amdgcn_mfma_f32_16x16x32_bf16(aq1, bk1, s[n], 0, 0, 0);
        }

        // P = 2^s; per-lane l partials; store bf16 P (swizzled)
#pragma unroll
        for (int n = 0; n < 4; ++n) {
            int colg = n * 2 + ((L & 15) >> 3);
#pragma unroll
            for (int r = 0; r < 4; ++r) {
                float p = EXP2(s[n][r]);
                lsum[r] += p;
                int row = 16 * w + (L >> 4) * 4 + r;
                Ps[row * 64 +
                   (((colg ^ (row & 7) ^ (((row >> 3) & 1) << 1)) & 7) << 3) +
                   (L & 7)] = f2bf(p);
            }
        }

        // PV (same-wave P rows -> no barrier needed)
        bf16x8 pa0 = *(const bf16x8*)&Ps[swz8(16 * w + (L & 15), (L >> 4))];
        bf16x8 pa1 = *(const bf16x8*)&Ps[swz8(16 * w + (L & 15), (L >> 4) + 4)];
#pragma unroll
        for (int c = 0; c < 4; ++c) {
            bf16x8 bv0 = *(const bf16x8*)&Vts[swz8(c * 16 + (L & 15), (L >> 4))];
            bf16x8 bv1 = *(const bf16x8*)&Vts[swz8(c * 16 + (L & 15), (L >> 4) + 4)];
            o[c] = __builtin_amdgcn_mfma_f32_16x16x32_bf16(pa0, bv0, o[c], 0, 0, 0);
            o[c] = __builtin_amdgcn_mfma_f32_16x16x32_bf16(pa1, bv1, o[c], 0, 0, 0);
        }
    }

    // epilogue: reduce l over the 16-lane col groups, normalize, pack, store
#pragma unroll
    for (int d = 1; d < 16; d <<= 1)
#pragma unroll
        for (int r = 0; r < 4; ++r) lsum[r] += __shfl_xor(lsum[r], d);
    float inv[4];
#pragma unroll
    for (int r = 0; r < 4; ++r) inv[r] = 1.f / lsum[r];

#pragma unroll
    for (int c = 0; c < 4; ++c)
#pragma unroll
        for (int r = 0; r < 4; ++r) {
            float val = o[c][r] * inv[r];
            float pvv = __shfl_xor(val, 1);
            if (!(L & 1)) {
                int sq = qt * 64 + 16 * w + (L >> 4) * 4 + r;
                int col = h * Cc + c * 16 + (L & 15);
                u32 pk2 = (u32)f2bf(val) | ((u32)f2bf(pvv) << 16);
                *(u32*)&res[(size_t)((b * Ss + sq) * Ff + qframe) * HC + col] = pk2;
            }
        }
}

// ---------------------------------------------------------------------------
extern "C" void kernel_launch(void* const* d_in, const int* in_sizes, int n_in,
                              void* d_out, int out_size, void* d_ws, size_t ws_size,
                              hipStream_t stream)
{
    (void)in_sizes; (void)n_in; (void)out_size; (void)ws_size;
    const float* x    = (const float*)d_in[0];
    const int*   dmsk = (const int*)  d_in[1];
    const float* Wq   = (const float*)d_in[2];
    const float* Wk   = (const float*)d_in[3];
    const float* Wv   = (const float*)d_in[4];
    const float* Wout = (const float*)d_in[5];
    const float* bout = (const float*)d_in[6];
    float* out = (float*)d_out;

    const size_t NE = (size_t)Mrows * HC;   // 9437184
    u16* xb  = (u16*)d_ws;
    u16* q   = xb  + NE;
    u16* kk  = q   + NE;
    u16* vv  = kk  + NE;
    u16* vT  = vv  + NE;
    u16* res = vT  + NE;
    u16* Wt  = res + NE;                    // 4 x 512x512

    convert_x_kernel<<<4608, 256, 0, stream>>>(x, xb);
    convert_w_kernel<<<dim3(8, 8, 4), 256, 0, stream>>>(Wq, Wk, Wv, Wout, Wt);
    gemm_qkv_kernel<<<dim3(144, 4, 3), 256, 0, stream>>>(xb, Wt, q, kk, vv);
    transpose_v_kernel<<<2304, 256, 0, stream>>>(vv, vT);
    attn_kernel<<<2304, 256, 0, stream>>>(q, kk, vT, dmsk, res);
    gemm_out_kernel<<<dim3(144, 4), 256, 0, stream>>>(
        res, Wt + (size_t)3 * 512 * 512, bout, out);
}

// Round 4
// 245.302 us; speedup vs baseline: 4.4307x; 1.0936x over previous
//
#include <hip/hip_runtime.h>
#include <math.h>

#define Bb 2
#define Ss 576
#define Ff 16
#define Hh 8
#define Cc 64
#define HC 512
#define Mrows (Bb * Ss * Ff)   // 18432

typedef __bf16 bf16x8 __attribute__((ext_vector_type(8)));
typedef float  f32x4  __attribute__((ext_vector_type(4)));
typedef unsigned short u16;
typedef unsigned int   u32;

#if __has_builtin(__builtin_amdgcn_exp2f)
#define EXP2(x) __builtin_amdgcn_exp2f(x)
#else
#define EXP2(x) exp2f(x)
#endif

// q pre-scale: 1/sqrt(C) * log2(e), folded into the q GEMM epilogue
#define QSCALE 0.18033688011112042f

__device__ __forceinline__ u16 f2bf(float f) {
    union { __bf16 b; u16 u; } cv;
    cv.b = (__bf16)f;          // hardware RNE convert
    return cv.u;
}

// XOR swizzles: group = 16B chunk of a row. Spreads b128 frag reads over all
// 8 bank-sets (round-3 verified: SQ_LDS_BANK_CONFLICT == 0).
__device__ __forceinline__ int swz8(int row, int g) {   // 64-u16 rows
    return row * 64 + (((g ^ (row & 7) ^ (((row >> 3) & 1) << 1)) & 7) << 3);
}
__device__ __forceinline__ int swzg(int row, int g) {   // 32-u16 rows
    return row * 32 + (((g ^ (row & 3)) & 3) << 3);
}

__device__ __forceinline__ uint4 pack8(float4 a, float4 b) {
    union { u16 s[8]; uint4 v; } u;
    u.s[0] = f2bf(a.x); u.s[1] = f2bf(a.y); u.s[2] = f2bf(a.z); u.s[3] = f2bf(a.w);
    u.s[4] = f2bf(b.x); u.s[5] = f2bf(b.y); u.s[6] = f2bf(b.z); u.s[7] = f2bf(b.w);
    return u.v;
}

// ---------------------------------------------------------------------------
// Transpose+convert weights: Wt[mat][n][k] = W[k][n], bf16.
// ---------------------------------------------------------------------------
__global__ __launch_bounds__(256) void convert_w_kernel(
    const float* __restrict__ W0, const float* __restrict__ W1,
    const float* __restrict__ W2, const float* __restrict__ W3,
    u16* __restrict__ Wt)
{
    __shared__ float Ts[64][65];
    const int mz = blockIdx.z;
    const float* W = (mz == 0) ? W0 : (mz == 1) ? W1 : (mz == 2) ? W2 : W3;
    u16* Wo = Wt + (size_t)mz * 512 * 512;
    const int k0 = blockIdx.x * 64, n0 = blockIdx.y * 64;
    const int t = threadIdx.x;
#pragma unroll
    for (int p = 0; p < 4; ++p) {
        int idx = t + p * 256;
        int row = idx >> 4, cg = idx & 15;
        *(float4*)&Ts[row][cg * 4] =
            *(const float4*)&W[(size_t)(k0 + row) * 512 + n0 + cg * 4];
    }
    __syncthreads();
#pragma unroll
    for (int p = 0; p < 2; ++p) {
        int idx = t + p * 256;
        int row = idx >> 3, cg = idx & 7;   // row = local n
        union { u16 s[8]; uint4 v; } u;
#pragma unroll
        for (int j = 0; j < 8; ++j) u.s[j] = f2bf(Ts[cg * 8 + j][row]);
        *(uint4*)&Wo[(size_t)(n0 + row) * 512 + k0 + cg * 8] = u.v;
    }
}

// ---------------------------------------------------------------------------
// Fused QKV GEMM.  A rows enumerate layout L = (b, f, s); x is read with the
// (b,s,f) -> (b,f,s) row remap and converted fp32->bf16 during LDS staging.
//   bid linear 1728:  mt = bid % 144  (so the 12 blocks sharing an A m-strip
//   are XCD-congruent: bid % 8 == mt % 8), mm = bid/144, nt = mm&3, mat = mm>>2.
//   mat 0 -> q (scaled QSCALE, bf16), 1 -> k (bf16), 2 -> vT[b,f,h,c,s] scatter.
// ---------------------------------------------------------------------------
__global__ __launch_bounds__(256) void qkv_kernel(
    const float* __restrict__ x, const u16* __restrict__ Wt,
    u16* __restrict__ q, u16* __restrict__ k, u16* __restrict__ vT)
{
    __shared__ u16 As[128 * 32];
    __shared__ u16 Bs[128 * 32];
    const int bi = blockIdx.x;
    const int mt = bi % 144;
    const int mm = bi / 144;
    const int nt = mm & 3, mat = mm >> 2;
    const int t = threadIdx.x;
    const int w = t >> 6, L = t & 63;
    const int m0 = mt * 128, n0 = nt * 128;
    const int wm = (w >> 1) * 64, wn = (w & 1) * 64;

    const int srow = t >> 2, scg = t & 3;
    // A rows m0+srow, m0+srow+64 -> x rows via (b,f,s) -> (b,s,f)
    const int ma0 = m0 + srow, ma1 = m0 + srow + 64;
    const int b0 = ma0 / 9216, r0 = ma0 % 9216, f0 = r0 / 576, s0 = r0 % 576;
    const int b1 = ma1 / 9216, r1 = ma1 % 9216, f1 = r1 / 576, s1 = r1 % 576;
    const float* xp0 = x + ((size_t)(b0 * 576 + s0) * 16 + f0) * 512 + scg * 8;
    const float* xp1 = x + ((size_t)(b1 * 576 + s1) * 16 + f1) * 512 + scg * 8;
    const u16* Bp = Wt + (size_t)mat * 512 * 512 + (size_t)(n0 + srow) * 512 + scg * 8;
    const int lo0 = swzg(srow, scg), lo1 = swzg(srow + 64, scg);

    float4 fa0 = *(const float4*)xp0, fa0b = *(const float4*)(xp0 + 4);
    float4 fa1 = *(const float4*)xp1, fa1b = *(const float4*)(xp1 + 4);
    uint4 ub0 = *(const uint4*)Bp;
    uint4 ub1 = *(const uint4*)(Bp + 64 * 512);

    f32x4 acc[4][4];
#pragma unroll
    for (int i = 0; i < 4; ++i)
#pragma unroll
        for (int j = 0; j < 4; ++j) acc[i][j] = (f32x4){0.f, 0.f, 0.f, 0.f};

    for (int k0 = 0; k0 < 512; k0 += 32) {
        __syncthreads();
        *(uint4*)&As[lo0] = pack8(fa0, fa0b);
        *(uint4*)&As[lo1] = pack8(fa1, fa1b);
        *(uint4*)&Bs[lo0] = ub0;
        *(uint4*)&Bs[lo1] = ub1;
        __syncthreads();
        if (k0 < 480) {
            fa0  = *(const float4*)(xp0 + k0 + 32);
            fa0b = *(const float4*)(xp0 + k0 + 36);
            fa1  = *(const float4*)(xp1 + k0 + 32);
            fa1b = *(const float4*)(xp1 + k0 + 36);
            ub0  = *(const uint4*)(Bp + k0 + 32);
            ub1  = *(const uint4*)(Bp + k0 + 32 + 64 * 512);
        }
        bf16x8 af[4], bfr[4];
#pragma unroll
        for (int i = 0; i < 4; ++i) {
            af[i]  = *(const bf16x8*)&As[swzg(wm + 16 * i + (L & 15), L >> 4)];
            bfr[i] = *(const bf16x8*)&Bs[swzg(wn + 16 * i + (L & 15), L >> 4)];
        }
#pragma unroll
        for (int i = 0; i < 4; ++i)
#pragma unroll
            for (int j = 0; j < 4; ++j)
                acc[i][j] = __builtin_amdgcn_mfma_f32_16x16x32_bf16(
                    af[i], bfr[j], acc[i][j], 0, 0, 0);
    }

    if (mat < 2) {
        u16* Cout = (mat == 0) ? q : k;
        const float scale = (mat == 0) ? QSCALE : 1.0f;
#pragma unroll
        for (int i = 0; i < 4; ++i)
#pragma unroll
            for (int j = 0; j < 4; ++j)
#pragma unroll
                for (int r = 0; r < 4; ++r) {
                    int row = m0 + wm + 16 * i + (L >> 4) * 4 + r;
                    int col = n0 + wn + 16 * j + (L & 15);
                    float vv = acc[i][j][r] * scale;
                    float pvv = __shfl_xor(vv, 1);
                    if (!(L & 1)) {
                        u32 pk2 = (u32)f2bf(vv) | ((u32)f2bf(pvv) << 16);
                        *(u32*)(Cout + (size_t)row * 512 + col) = pk2;
                    }
                }
    } else {
        // vT[b][f][h][c][s]: 4 acc rows = 4 contiguous s (8 B store)
#pragma unroll
        for (int i = 0; i < 4; ++i) {
            int row = m0 + wm + 16 * i + (L >> 4) * 4;   // s aligned to 4
            int bb = row / 9216, rr = row % 9216;
            int f = rr / 576, s = rr % 576;
#pragma unroll
            for (int j = 0; j < 4; ++j) {
                int col = n0 + wn + 16 * j + (L & 15);
                int h = col >> 6, c = col & 63;
                union { u16 s4[4]; uint2 v; } u;
#pragma unroll
                for (int r = 0; r < 4; ++r) u.s4[r] = f2bf(acc[i][j][r]);
                *(uint2*)&vT[((((size_t)(bb * 16 + f) * 8 + h) * 64 + c) * 576) + s] = u.v;
            }
        }
    }
}

// ---------------------------------------------------------------------------
// Output GEMM: out[(b,s,f)] = res[(b,f,s)] @ Wout + bout.  bid: mt = bid%144.
// ---------------------------------------------------------------------------
__global__ __launch_bounds__(256) void gemm_out_kernel(
    const u16* __restrict__ res, const u16* __restrict__ Wt3,
    const float* __restrict__ bout, float* __restrict__ out)
{
    __shared__ u16 As[128 * 32];
    __shared__ u16 Bs[128 * 32];
    const int bi = blockIdx.x;
    const int mt = bi % 144, nt = bi / 144;
    const int t = threadIdx.x;
    const int w = t >> 6, L = t & 63;
    const int m0 = mt * 128, n0 = nt * 128;
    const int wm = (w >> 1) * 64, wn = (w & 1) * 64;

    const int srow = t >> 2, scg = t & 3;
    const u16* Ap = res + (size_t)(m0 + srow) * 512 + scg * 8;
    const u16* Bp = Wt3 + (size_t)(n0 + srow) * 512 + scg * 8;
    const int lo0 = swzg(srow, scg), lo1 = swzg(srow + 64, scg);

    uint4 ua0 = *(const uint4*)Ap;
    uint4 ua1 = *(const uint4*)(Ap + 64 * 512);
    uint4 ub0 = *(const uint4*)Bp;
    uint4 ub1 = *(const uint4*)(Bp + 64 * 512);

    f32x4 acc[4][4];
#pragma unroll
    for (int i = 0; i < 4; ++i)
#pragma unroll
        for (int j = 0; j < 4; ++j) acc[i][j] = (f32x4){0.f, 0.f, 0.f, 0.f};

    for (int k0 = 0; k0 < 512; k0 += 32) {
        __syncthreads();
        *(uint4*)&As[lo0] = ua0;
        *(uint4*)&As[lo1] = ua1;
        *(uint4*)&Bs[lo0] = ub0;
        *(uint4*)&Bs[lo1] = ub1;
        __syncthreads();
        if (k0 < 480) {
            ua0 = *(const uint4*)(Ap + k0 + 32);
            ua1 = *(const uint4*)(Ap + k0 + 32 + 64 * 512);
            ub0 = *(const uint4*)(Bp + k0 + 32);
            ub1 = *(const uint4*)(Bp + k0 + 32 + 64 * 512);
        }
        bf16x8 af[4], bfr[4];
#pragma unroll
        for (int i = 0; i < 4; ++i) {
            af[i]  = *(const bf16x8*)&As[swzg(wm + 16 * i + (L & 15), L >> 4)];
            bfr[i] = *(const bf16x8*)&Bs[swzg(wn + 16 * i + (L & 15), L >> 4)];
        }
#pragma unroll
        for (int i = 0; i < 4; ++i)
#pragma unroll
            for (int j = 0; j < 4; ++j)
                acc[i][j] = __builtin_amdgcn_mfma_f32_16x16x32_bf16(
                    af[i], bfr[j], acc[i][j], 0, 0, 0);
    }

#pragma unroll
    for (int i = 0; i < 4; ++i)
#pragma unroll
        for (int r = 0; r < 4; ++r) {
            int row = m0 + wm + 16 * i + (L >> 4) * 4 + r;
            int bb = row / 9216, rr = row % 9216;
            int f = rr / 576, s = rr % 576;
            size_t obase = ((size_t)(bb * 576 + s) * 16 + f) * 512;
#pragma unroll
            for (int j = 0; j < 4; ++j) {
                int col = n0 + wn + 16 * j + (L & 15);
                out[obase + col] = acc[i][j][r] + bout[col];
            }
        }
}

// ---------------------------------------------------------------------------
// MFMA flash attention (layout L).  mode0 = resq (first 144 blocks, 81 key
// tiles each), mode1 = ress.  XCD-congruent grouping: blocks sharing a K/V
// set have bid % 8 equal.  Q A-frags loaded direct from global (no Qs LDS).
// ---------------------------------------------------------------------------
__global__ __launch_bounds__(256) void attn_kernel(
    const u16* __restrict__ q, const u16* __restrict__ k,
    const u16* __restrict__ vT, const int* __restrict__ dm,
    u16* __restrict__ res)
{
    __shared__ u16 Ks[64 * 64];    // [key][c]    swizzled
    __shared__ u16 Vts[64 * 64];   // [c][key]    swizzled
    __shared__ u16 Ps[64 * 64];    // [q][key]    swizzled, bf16
    __shared__ int fl[16];
    __shared__ int df_s;

    const int t = threadIdx.x;
    const int w = t >> 6, L = t & 63;
    const int bi = blockIdx.x;

    int b, h, qt, qframe, mode;
    if (bi < 144) {                 // resq groups: g = bi & 15 (16 ≡ 0 mod 8)
        mode = 0;
        qt = bi >> 4;
        int g = bi & 15;
        b = g >> 3; h = g & 7; qframe = 0;
    } else {                        // ress groups: g = u % 240 (240 ≡ 0 mod 8)
        mode = 1;
        int u = bi - 144;
        int g = u % 240;
        qt = u / 240;
        b = g / 120;
        int rr = g % 120;
        qframe = 1 + (rr >> 3); h = rr & 7;
    }

    if (t == 0) {
        if (mode == 0) {
            int n = 0;
            fl[n++] = 0; fl[n++] = 1;
            for (int j = 0; j < Ff - 2; ++j)
                if (dm[b * (Ff - 2) + j] == 0) fl[n++] = 2 + j;
            df_s = n;
        } else df_s = 1;
    }
    __syncthreads();

    const int nkt = (mode == 0) ? df_s * 9 : 9;

    // Q A-frags direct from global (one time): rows 16w+(L&15), k = (L>>4)*8
    const u16* qbase = q + ((size_t)(b * 16 + qframe) * 576 + qt * 64 + 16 * w + (L & 15)) * 512
                         + h * 64 + (L >> 4) * 8;
    bf16x8 aq0 = *(const bf16x8*)qbase;
    bf16x8 aq1 = *(const bf16x8*)(qbase + 32);

    float lsum[4] = {0.f, 0.f, 0.f, 0.f};
    f32x4 o[4];
#pragma unroll
    for (int c = 0; c < 4; ++c) o[c] = (f32x4){0.f, 0.f, 0.f, 0.f};

    const int srow = t >> 3, scg = t & 7;   // staging rows 0..31 (+32)
    uint4 pk0, pk1, pv0, pv1;
    {   // preload tile 0 (frame 0 for mode0 — fl[0] is always 0)
        int kf0 = (mode == 0) ? 0 : qframe;
        const u16* kpp = k + ((size_t)(b * 16 + kf0) * 576 + srow) * 512 + h * 64 + scg * 8;
        pk0 = *(const uint4*)kpp;
        pk1 = *(const uint4*)(kpp + 32 * 512);
        const u16* vpp = vT + (((size_t)(b * 16 + kf0) * 8 + h) * 64 + srow) * 576 + scg * 8;
        pv0 = *(const uint4*)vpp;
        pv1 = *(const uint4*)(vpp + 32 * 576);
    }

    const int lko0 = swz8(srow, scg), lko1 = swz8(srow + 32, scg);

    for (int kt = 0; kt < nkt; ++kt) {
        __syncthreads();                    // all waves done reading prev tiles
        *(uint4*)&Ks[lko0]  = pk0;
        *(uint4*)&Ks[lko1]  = pk1;
        *(uint4*)&Vts[lko0] = pv0;
        *(uint4*)&Vts[lko1] = pv1;
        __syncthreads();

        if (kt + 1 < nkt) {                 // prefetch next tile into regs
            int kn = kt + 1, kf, s0;
            if (mode == 0) { int fi = kn / 9; kf = fl[fi]; s0 = (kn - fi * 9) * 64; }
            else           { kf = qframe;     s0 = kn * 64; }
            const u16* kpp = k + ((size_t)(b * 16 + kf) * 576 + s0 + srow) * 512 + h * 64 + scg * 8;
            pk0 = *(const uint4*)kpp;
            pk1 = *(const uint4*)(kpp + 32 * 512);
            const u16* vpp = vT + (((size_t)(b * 16 + kf) * 8 + h) * 64 + srow) * 576 + s0 + scg * 8;
            pv0 = *(const uint4*)vpp;
            pv1 = *(const uint4*)(vpp + 32 * 576);
        }

        // S = Q K^T  (wave w: its 16 queries x 64 keys)
        f32x4 s[4];
#pragma unroll
        for (int n = 0; n < 4; ++n) s[n] = (f32x4){0.f, 0.f, 0.f, 0.f};
#pragma unroll
        for (int n = 0; n < 4; ++n) {
            bf16x8 bk0 = *(const bf16x8*)&Ks[swz8(n * 16 + (L & 15), (L >> 4))];
            bf16x8 bk1 = *(const bf16x8*)&Ks[swz8(n * 16 + (L & 15), (L >> 4) + 4)];
            s[n] = __builtin_amdgcn_mfma_f32_16x16x32_bf16(aq0, bk0, s[n], 0, 0, 0);
            s[n] = __builtin_amdgcn_mfma_f32_16x16x32_bf16(aq1, bk1, s[n], 0, 0, 0);
        }

        // P = 2^s; per-lane l partials; store bf16 P (swizzled)
#pragma unroll
        for (int n = 0; n < 4; ++n) {
            int colg = n * 2 + ((L & 15) >> 3);
#pragma unroll
            for (int r = 0; r < 4; ++r) {
                float p = EXP2(s[n][r]);
                lsum[r] += p;
                int row = 16 * w + (L >> 4) * 4 + r;
                Ps[row * 64 +
                   (((colg ^ (row & 7) ^ (((row >> 3) & 1) << 1)) & 7) << 3) +
                   (L & 7)] = f2bf(p);
            }
        }

        // PV (same-wave P rows -> no barrier needed)
        bf16x8 pa0 = *(const bf16x8*)&Ps[swz8(16 * w + (L & 15), (L >> 4))];
        bf16x8 pa1 = *(const bf16x8*)&Ps[swz8(16 * w + (L & 15), (L >> 4) + 4)];
#pragma unroll
        for (int c = 0; c < 4; ++c) {
            bf16x8 bv0 = *(const bf16x8*)&Vts[swz8(c * 16 + (L & 15), (L >> 4))];
            bf16x8 bv1 = *(const bf16x8*)&Vts[swz8(c * 16 + (L & 15), (L >> 4) + 4)];
            o[c] = __builtin_amdgcn_mfma_f32_16x16x32_bf16(pa0, bv0, o[c], 0, 0, 0);
            o[c] = __builtin_amdgcn_mfma_f32_16x16x32_bf16(pa1, bv1, o[c], 0, 0, 0);
        }
    }

    // epilogue: reduce l over 16-lane groups, normalize, pack, store
#pragma unroll
    for (int d = 1; d < 16; d <<= 1)
#pragma unroll
        for (int r = 0; r < 4; ++r) lsum[r] += __shfl_xor(lsum[r], d);
    float inv[4];
#pragma unroll
    for (int r = 0; r < 4; ++r) inv[r] = 1.f / lsum[r];

#pragma unroll
    for (int c = 0; c < 4; ++c)
#pragma unroll
        for (int r = 0; r < 4; ++r) {
            float val = o[c][r] * inv[r];
            float pvv = __shfl_xor(val, 1);
            if (!(L & 1)) {
                int sq = qt * 64 + 16 * w + (L >> 4) * 4 + r;
                int col = h * Cc + c * 16 + (L & 15);
                *(u32*)&res[((size_t)(b * 16 + qframe) * 576 + sq) * 512 + col] =
                    (u32)f2bf(val) | ((u32)f2bf(pvv) << 16);
            }
        }
}

// ---------------------------------------------------------------------------
extern "C" void kernel_launch(void* const* d_in, const int* in_sizes, int n_in,
                              void* d_out, int out_size, void* d_ws, size_t ws_size,
                              hipStream_t stream)
{
    (void)in_sizes; (void)n_in; (void)out_size; (void)ws_size;
    const float* x    = (const float*)d_in[0];
    const int*   dmsk = (const int*)  d_in[1];
    const float* Wq   = (const float*)d_in[2];
    const float* Wk   = (const float*)d_in[3];
    const float* Wv   = (const float*)d_in[4];
    const float* Wout = (const float*)d_in[5];
    const float* bout = (const float*)d_in[6];
    float* out = (float*)d_out;

    const size_t NE = (size_t)Mrows * HC;   // 9437184
    u16* q   = (u16*)d_ws;                  // [b,f,s,hc]
    u16* kk  = q   + NE;                    // [b,f,s,hc]
    u16* vT  = kk  + NE;                    // [b,f,h,c,s]
    u16* res = vT  + NE;                    // [b,f,s,hc]
    u16* Wt  = res + NE;                    // 4 x 512x512 (n-major)

    convert_w_kernel<<<dim3(8, 8, 4), 256, 0, stream>>>(Wq, Wk, Wv, Wout, Wt);
    qkv_kernel<<<1728, 256, 0, stream>>>(x, Wt, q, kk, vT);
    attn_kernel<<<2304, 256, 0, stream>>>(q, kk, vT, dmsk, res);
    gemm_out_kernel<<<576, 256, 0, stream>>>(
        res, Wt + (size_t)3 * 512 * 512, bout, out);
}

// Round 5
// 240.180 us; speedup vs baseline: 4.5252x; 1.0213x over previous
//
#include <hip/hip_runtime.h>
#include <math.h>

#define Bb 2
#define Ss 576
#define Ff 16
#define Hh 8
#define Cc 64
#define HC 512
#define Mrows (Bb * Ss * Ff)   // 18432

typedef __bf16 bf16x8 __attribute__((ext_vector_type(8)));
typedef float  f32x4  __attribute__((ext_vector_type(4)));
typedef float  f32x16 __attribute__((ext_vector_type(16)));
typedef unsigned short u16;
typedef unsigned int   u32;

#if __has_builtin(__builtin_amdgcn_exp2f)
#define EXP2(x) __builtin_amdgcn_exp2f(x)
#else
#define EXP2(x) exp2f(x)
#endif

// q pre-scale: 1/sqrt(C) * log2(e), folded into the q GEMM epilogue
#define QSCALE 0.18033688011112042f

__device__ __forceinline__ u16 f2bf(float f) {
    union { __bf16 b; u16 u; } cv;
    cv.b = (__bf16)f;          // hardware RNE convert
    return cv.u;
}

__device__ __forceinline__ f32x16 zero16() {
    f32x16 z;
#pragma unroll
    for (int i = 0; i < 16; ++i) z[i] = 0.f;
    return z;
}

// XOR swizzles (round-3/4 verified: SQ_LDS_BANK_CONFLICT == 0)
__device__ __forceinline__ int swz8(int row, int g) {   // 64-u16 rows
    return row * 64 + (((g ^ (row & 7) ^ (((row >> 3) & 1) << 1)) & 7) << 3);
}
__device__ __forceinline__ int swzg(int row, int g) {   // 32-u16 rows
    return row * 32 + (((g ^ (row & 3)) & 3) << 3);
}

__device__ __forceinline__ uint4 pack8(float4 a, float4 b) {
    union { u16 s[8]; uint4 v; } u;
    u.s[0] = f2bf(a.x); u.s[1] = f2bf(a.y); u.s[2] = f2bf(a.z); u.s[3] = f2bf(a.w);
    u.s[4] = f2bf(b.x); u.s[5] = f2bf(b.y); u.s[6] = f2bf(b.z); u.s[7] = f2bf(b.w);
    return u.v;
}

// ---------------------------------------------------------------------------
// Transpose+convert weights: Wt[mat][n][k] = W[k][n], bf16.
// ---------------------------------------------------------------------------
__global__ __launch_bounds__(256) void convert_w_kernel(
    const float* __restrict__ W0, const float* __restrict__ W1,
    const float* __restrict__ W2, const float* __restrict__ W3,
    u16* __restrict__ Wt)
{
    __shared__ float Ts[64][65];
    const int mz = blockIdx.z;
    const float* W = (mz == 0) ? W0 : (mz == 1) ? W1 : (mz == 2) ? W2 : W3;
    u16* Wo = Wt + (size_t)mz * 512 * 512;
    const int k0 = blockIdx.x * 64, n0 = blockIdx.y * 64;
    const int t = threadIdx.x;
#pragma unroll
    for (int p = 0; p < 4; ++p) {
        int idx = t + p * 256;
        int row = idx >> 4, cg = idx & 15;
        *(float4*)&Ts[row][cg * 4] =
            *(const float4*)&W[(size_t)(k0 + row) * 512 + n0 + cg * 4];
    }
    __syncthreads();
#pragma unroll
    for (int p = 0; p < 2; ++p) {
        int idx = t + p * 256;
        int row = idx >> 3, cg = idx & 7;   // row = local n
        union { u16 s[8]; uint4 v; } u;
#pragma unroll
        for (int j = 0; j < 8; ++j) u.s[j] = f2bf(Ts[cg * 8 + j][row]);
        *(uint4*)&Wo[(size_t)(n0 + row) * 512 + k0 + cg * 8] = u.v;
    }
}

// ---------------------------------------------------------------------------
// Fused QKV GEMM (unchanged from round 4).
// ---------------------------------------------------------------------------
__global__ __launch_bounds__(256) void qkv_kernel(
    const float* __restrict__ x, const u16* __restrict__ Wt,
    u16* __restrict__ q, u16* __restrict__ k, u16* __restrict__ vT)
{
    __shared__ u16 As[128 * 32];
    __shared__ u16 Bs[128 * 32];
    const int bi = blockIdx.x;
    const int mt = bi % 144;
    const int mm = bi / 144;
    const int nt = mm & 3, mat = mm >> 2;
    const int t = threadIdx.x;
    const int w = t >> 6, L = t & 63;
    const int m0 = mt * 128, n0 = nt * 128;
    const int wm = (w >> 1) * 64, wn = (w & 1) * 64;

    const int srow = t >> 2, scg = t & 3;
    const int ma0 = m0 + srow, ma1 = m0 + srow + 64;
    const int b0 = ma0 / 9216, r0 = ma0 % 9216, f0 = r0 / 576, s0 = r0 % 576;
    const int b1 = ma1 / 9216, r1 = ma1 % 9216, f1 = r1 / 576, s1 = r1 % 576;
    const float* xp0 = x + ((size_t)(b0 * 576 + s0) * 16 + f0) * 512 + scg * 8;
    const float* xp1 = x + ((size_t)(b1 * 576 + s1) * 16 + f1) * 512 + scg * 8;
    const u16* Bp = Wt + (size_t)mat * 512 * 512 + (size_t)(n0 + srow) * 512 + scg * 8;
    const int lo0 = swzg(srow, scg), lo1 = swzg(srow + 64, scg);

    float4 fa0 = *(const float4*)xp0, fa0b = *(const float4*)(xp0 + 4);
    float4 fa1 = *(const float4*)xp1, fa1b = *(const float4*)(xp1 + 4);
    uint4 ub0 = *(const uint4*)Bp;
    uint4 ub1 = *(const uint4*)(Bp + 64 * 512);

    f32x4 acc[4][4];
#pragma unroll
    for (int i = 0; i < 4; ++i)
#pragma unroll
        for (int j = 0; j < 4; ++j) acc[i][j] = (f32x4){0.f, 0.f, 0.f, 0.f};

    for (int k0 = 0; k0 < 512; k0 += 32) {
        __syncthreads();
        *(uint4*)&As[lo0] = pack8(fa0, fa0b);
        *(uint4*)&As[lo1] = pack8(fa1, fa1b);
        *(uint4*)&Bs[lo0] = ub0;
        *(uint4*)&Bs[lo1] = ub1;
        __syncthreads();
        if (k0 < 480) {
            fa0  = *(const float4*)(xp0 + k0 + 32);
            fa0b = *(const float4*)(xp0 + k0 + 36);
            fa1  = *(const float4*)(xp1 + k0 + 32);
            fa1b = *(const float4*)(xp1 + k0 + 36);
            ub0  = *(const uint4*)(Bp + k0 + 32);
            ub1  = *(const uint4*)(Bp + k0 + 32 + 64 * 512);
        }
        bf16x8 af[4], bfr[4];
#pragma unroll
        for (int i = 0; i < 4; ++i) {
            af[i]  = *(const bf16x8*)&As[swzg(wm + 16 * i + (L & 15), L >> 4)];
            bfr[i] = *(const bf16x8*)&Bs[swzg(wn + 16 * i + (L & 15), L >> 4)];
        }
#pragma unroll
        for (int i = 0; i < 4; ++i)
#pragma unroll
            for (int j = 0; j < 4; ++j)
                acc[i][j] = __builtin_amdgcn_mfma_f32_16x16x32_bf16(
                    af[i], bfr[j], acc[i][j], 0, 0, 0);
    }

    if (mat < 2) {
        u16* Cout = (mat == 0) ? q : k;
        const float scale = (mat == 0) ? QSCALE : 1.0f;
#pragma unroll
        for (int i = 0; i < 4; ++i)
#pragma unroll
            for (int j = 0; j < 4; ++j)
#pragma unroll
                for (int r = 0; r < 4; ++r) {
                    int row = m0 + wm + 16 * i + (L >> 4) * 4 + r;
                    int col = n0 + wn + 16 * j + (L & 15);
                    float vv = acc[i][j][r] * scale;
                    float pvv = __shfl_xor(vv, 1);
                    if (!(L & 1)) {
                        u32 pk2 = (u32)f2bf(vv) | ((u32)f2bf(pvv) << 16);
                        *(u32*)(Cout + (size_t)row * 512 + col) = pk2;
                    }
                }
    } else {
#pragma unroll
        for (int i = 0; i < 4; ++i) {
            int row = m0 + wm + 16 * i + (L >> 4) * 4;   // s aligned to 4
            int bb = row / 9216, rr = row % 9216;
            int f = rr / 576, s = rr % 576;
#pragma unroll
            for (int j = 0; j < 4; ++j) {
                int col = n0 + wn + 16 * j + (L & 15);
                int h = col >> 6, c = col & 63;
                union { u16 s4[4]; uint2 v; } u;
#pragma unroll
                for (int r = 0; r < 4; ++r) u.s4[r] = f2bf(acc[i][j][r]);
                *(uint2*)&vT[((((size_t)(bb * 16 + f) * 8 + h) * 64 + c) * 576) + s] = u.v;
            }
        }
    }
}

// ---------------------------------------------------------------------------
// Output GEMM (unchanged from round 4).
// ---------------------------------------------------------------------------
__global__ __launch_bounds__(256) void gemm_out_kernel(
    const u16* __restrict__ res, const u16* __restrict__ Wt3,
    const float* __restrict__ bout, float* __restrict__ out)
{
    __shared__ u16 As[128 * 32];
    __shared__ u16 Bs[128 * 32];
    const int bi = blockIdx.x;
    const int mt = bi % 144, nt = bi / 144;
    const int t = threadIdx.x;
    const int w = t >> 6, L = t & 63;
    const int m0 = mt * 128, n0 = nt * 128;
    const int wm = (w >> 1) * 64, wn = (w & 1) * 64;

    const int srow = t >> 2, scg = t & 3;
    const u16* Ap = res + (size_t)(m0 + srow) * 512 + scg * 8;
    const u16* Bp = Wt3 + (size_t)(n0 + srow) * 512 + scg * 8;
    const int lo0 = swzg(srow, scg), lo1 = swzg(srow + 64, scg);

    uint4 ua0 = *(const uint4*)Ap;
    uint4 ua1 = *(const uint4*)(Ap + 64 * 512);
    uint4 ub0 = *(const uint4*)Bp;
    uint4 ub1 = *(const uint4*)(Bp + 64 * 512);

    f32x4 acc[4][4];
#pragma unroll
    for (int i = 0; i < 4; ++i)
#pragma unroll
        for (int j = 0; j < 4; ++j) acc[i][j] = (f32x4){0.f, 0.f, 0.f, 0.f};

    for (int k0 = 0; k0 < 512; k0 += 32) {
        __syncthreads();
        *(uint4*)&As[lo0] = ua0;
        *(uint4*)&As[lo1] = ua1;
        *(uint4*)&Bs[lo0] = ub0;
        *(uint4*)&Bs[lo1] = ub1;
        __syncthreads();
        if (k0 < 480) {
            ua0 = *(const uint4*)(Ap + k0 + 32);
            ua1 = *(const uint4*)(Ap + k0 + 32 + 64 * 512);
            ub0 = *(const uint4*)(Bp + k0 + 32);
            ub1 = *(const uint4*)(Bp + k0 + 32 + 64 * 512);
        }
        bf16x8 af[4], bfr[4];
#pragma unroll
        for (int i = 0; i < 4; ++i) {
            af[i]  = *(const bf16x8*)&As[swzg(wm + 16 * i + (L & 15), L >> 4)];
            bfr[i] = *(const bf16x8*)&Bs[swzg(wn + 16 * i + (L & 15), L >> 4)];
        }
#pragma unroll
        for (int i = 0; i < 4; ++i)
#pragma unroll
            for (int j = 0; j < 4; ++j)
                acc[i][j] = __builtin_amdgcn_mfma_f32_16x16x32_bf16(
                    af[i], bfr[j], acc[i][j], 0, 0, 0);
    }

#pragma unroll
    for (int i = 0; i < 4; ++i)
#pragma unroll
        for (int r = 0; r < 4; ++r) {
            int row = m0 + wm + 16 * i + (L >> 4) * 4 + r;
            int bb = row / 9216, rr = row % 9216;
            int f = rr / 576, s = rr % 576;
            size_t obase = ((size_t)(bb * 576 + s) * 16 + f) * 512;
#pragma unroll
            for (int j = 0; j < 4; ++j) {
                int col = n0 + wn + 16 * j + (L & 15);
                out[obase + col] = acc[i][j][r] + bout[col];
            }
        }
}

// ---------------------------------------------------------------------------
// MFMA flash attention, 32x32x16 transposed pipeline.
//   Wave = 32 queries; block = 4 waves = 128 q (tail q-tile: 2 active waves).
//   EVERY block: one (keyframe kf) x 9 s-tiles of 64 keys  -> perfect balance.
//   mode0 (resq, first 720 blocks): kf = fl[fi]; writes fp32 partials (o,l).
//   mode1 (ress): kf = qframe; writes res directly.
//   S^T = K Q^T (m=key,n=q,k=c);  O^T = V^T P^T (m=c,n=q,k=key).
//   P: C-layout -> 8 packed uint2 LDS writes; read back as b128 B-frags.
// ---------------------------------------------------------------------------
__global__ __launch_bounds__(256, 4) void attn_kernel(
    const u16* __restrict__ q, const u16* __restrict__ k,
    const u16* __restrict__ vT, const int* __restrict__ dm,
    u16* __restrict__ res, float* __restrict__ po, float* __restrict__ pl)
{
    __shared__ u16 Ks[64 * 64];    // [key][c]  swizzled
    __shared__ u16 Vts[64 * 64];   // [c][key]  swizzled
    __shared__ u16 Ps[128 * 64];   // [q][key]  swizzled, bf16
    __shared__ int fl[16];

    const int t = threadIdx.x;
    const int w = t >> 6, L = t & 63;
    const int half = L >> 5, l31 = L & 31;
    const int bi = blockIdx.x;

    int b, h, qt, qframe, fi, mode;
    if (bi < 720) {                 // mode0: bid = qt*144 + (bh*9 + fi)
        mode = 0;
        qt = bi / 144;
        int g = bi % 144;           // 144 ≡ 0 mod 8 -> (bh,fi) XCD-congruent
        int bh = g / 9; fi = g % 9;
        b = bh >> 3; h = bh & 7; qframe = 0;
    } else {
        mode = 1;
        int u = bi - 720;
        int g = u % 240;            // 240 ≡ 0 mod 8
        qt = u / 240;
        b = g / 120;
        int rr = g % 120;
        qframe = 1 + (rr >> 3); h = rr & 7; fi = 0;
    }

    if (t == 0) {
        int n = 0;
        fl[n++] = 0; fl[n++] = 1;
        for (int j = 0; j < Ff - 2; ++j)
            if (dm[b * (Ff - 2) + j] == 0) fl[n++] = 2 + j;
    }
    __syncthreads();

    const int kf = (mode == 0) ? fl[fi] : qframe;

    const int q0 = qt * 128;
    const bool active = (q0 + 32 * w) < Ss;
    const int qrow = q0 + 32 * w + l31;       // global query row (if active)
    const int prow = 32 * w + l31;            // Ps row

    // Q B-frags: B[n=q=l31][k=c=16*ks+8*half+j], direct from global
    bf16x8 qf[4];
    if (active) {
        const u16* qp = q + ((size_t)(b * 16 + qframe) * Ss + qrow) * 512 + h * 64 + 8 * half;
#pragma unroll
        for (int ks = 0; ks < 4; ++ks) qf[ks] = *(const bf16x8*)(qp + 16 * ks);
    }

    float lsum = 0.f;
    f32x16 o[2] = {zero16(), zero16()};

    const int srow = t >> 2, sc2 = (t & 3) * 2;
    const int lk0 = swz8(srow, sc2), lk1 = swz8(srow, sc2 + 1);
    const u16* kbase = k + ((size_t)(b * 16 + kf) * Ss) * 512 + h * 64;
    const u16* vbase = vT + (((size_t)(b * 16 + kf) * 8 + h) * 64) * (size_t)Ss;

    uint4 ka, kb2, va, vb2;
    {
        const u16* kp = kbase + (size_t)srow * 512 + sc2 * 8;
        ka  = *(const uint4*)kp;
        kb2 = *(const uint4*)(kp + 8);
        const u16* vp = vbase + (size_t)srow * Ss + sc2 * 8;
        va  = *(const uint4*)vp;
        vb2 = *(const uint4*)(vp + 8);
    }

    for (int kt = 0; kt < 9; ++kt) {
        __syncthreads();
        *(uint4*)&Ks[lk0]  = ka;
        *(uint4*)&Ks[lk1]  = kb2;
        *(uint4*)&Vts[lk0] = va;
        *(uint4*)&Vts[lk1] = vb2;
        __syncthreads();

        if (kt < 8) {
            int s0 = (kt + 1) * 64;
            const u16* kp = kbase + (size_t)(s0 + srow) * 512 + sc2 * 8;
            ka  = *(const uint4*)kp;
            kb2 = *(const uint4*)(kp + 8);
            const u16* vp = vbase + (size_t)srow * Ss + s0 + sc2 * 8;
            va  = *(const uint4*)vp;
            vb2 = *(const uint4*)(vp + 8);
        }

        if (active) {
            // S^T: A=K[key][c] frags, B=Q frags
            f32x16 st[2] = {zero16(), zero16()};
#pragma unroll
            for (int ks = 0; ks < 4; ++ks) {
                bf16x8 a0 = *(const bf16x8*)&Ks[swz8(l31,      2 * ks + half)];
                bf16x8 a1 = *(const bf16x8*)&Ks[swz8(32 + l31, 2 * ks + half)];
                st[0] = __builtin_amdgcn_mfma_f32_32x32x16_bf16(a0, qf[ks], st[0], 0, 0, 0);
                st[1] = __builtin_amdgcn_mfma_f32_32x32x16_bf16(a1, qf[ks], st[1], 0, 0, 0);
            }
            // P = 2^s; pack 4 contiguous keys per uint2 (C/D rows r+8g+4*half)
            const int rsw = (prow & 7) ^ (((prow >> 3) & 1) << 1);
#pragma unroll
            for (int mg = 0; mg < 2; ++mg)
#pragma unroll
                for (int g = 0; g < 4; ++g) {
                    float p0 = EXP2(st[mg][4 * g + 0]);
                    float p1 = EXP2(st[mg][4 * g + 1]);
                    float p2 = EXP2(st[mg][4 * g + 2]);
                    float p3 = EXP2(st[mg][4 * g + 3]);
                    lsum += (p0 + p1) + (p2 + p3);
                    union { u16 s4[4]; uint2 v; } u;
                    u.s4[0] = f2bf(p0); u.s4[1] = f2bf(p1);
                    u.s4[2] = f2bf(p2); u.s4[3] = f2bf(p3);
                    int ch = 4 * mg + g;
                    *(uint2*)&Ps[prow * 64 + (((ch ^ rsw) & 7) << 3) + half * 4] = u.v;
                }
            // O^T += V^T P^T  (same-wave P rows -> no barrier)
#pragma unroll
            for (int ks = 0; ks < 4; ++ks) {
                bf16x8 pb = *(const bf16x8*)&Ps[swz8(prow, 2 * ks + half)];
                bf16x8 v0 = *(const bf16x8*)&Vts[swz8(l31,      2 * ks + half)];
                bf16x8 v1 = *(const bf16x8*)&Vts[swz8(32 + l31, 2 * ks + half)];
                o[0] = __builtin_amdgcn_mfma_f32_32x32x16_bf16(v0, pb, o[0], 0, 0, 0);
                o[1] = __builtin_amdgcn_mfma_f32_32x32x16_bf16(v1, pb, o[1], 0, 0, 0);
            }
        }
    }

    if (!active) return;
    lsum += __shfl_xor(lsum, 32);

    if (mode == 1) {
        float inv = 1.f / lsum;
        u16* rp = res + ((size_t)(b * 16 + qframe) * Ss + qrow) * 512 + h * 64;
#pragma unroll
        for (int cg = 0; cg < 2; ++cg)
#pragma unroll
            for (int g = 0; g < 4; ++g) {
                union { u16 s4[4]; uint2 v; } u;
#pragma unroll
                for (int r = 0; r < 4; ++r) u.s4[r] = f2bf(o[cg][4 * g + r] * inv);
                *(uint2*)&rp[32 * cg + 8 * g + 4 * half] = u.v;
            }
    } else {
        // fp32 partials for the frame-split merge (no-max softmax: just sums)
        int bh = b * 8 + h;
        float* pp = po + ((size_t)(fi * 16 + bh) * Ss + qrow) * 64;
#pragma unroll
        for (int cg = 0; cg < 2; ++cg)
#pragma unroll
            for (int g = 0; g < 4; ++g) {
                float4 v4 = make_float4(o[cg][4 * g + 0], o[cg][4 * g + 1],
                                        o[cg][4 * g + 2], o[cg][4 * g + 3]);
                *(float4*)&pp[32 * cg + 8 * g + 4 * half] = v4;
            }
        if (half == 0) pl[(size_t)(fi * 16 + bh) * Ss + qrow] = lsum;
    }
}

// ---------------------------------------------------------------------------
// Merge the 9 frame-partials of resq: res[...,frame0,...] = Σo / Σl.
// ---------------------------------------------------------------------------
__global__ __launch_bounds__(256) void merge_kernel(
    const float* __restrict__ po, const float* __restrict__ pl,
    u16* __restrict__ res)
{
    int tid = blockIdx.x * 256 + threadIdx.x;   // 147456 = 16*576*16
    int c4 = tid & 15;
    int rem = tid >> 4;
    int qg = rem % Ss;
    int bh = rem / Ss;
    int b = bh >> 3, h = bh & 7;
    float4 acc = make_float4(0.f, 0.f, 0.f, 0.f);
    float ls = 0.f;
#pragma unroll
    for (int fi = 0; fi < 9; ++fi) {
        const float4 v = *(const float4*)&po[((size_t)(fi * 16 + bh) * Ss + qg) * 64 + c4 * 4];
        acc.x += v.x; acc.y += v.y; acc.z += v.z; acc.w += v.w;
        ls += pl[(size_t)(fi * 16 + bh) * Ss + qg];
    }
    float inv = 1.f / ls;
    union { u16 s4[4]; uint2 v; } u;
    u.s4[0] = f2bf(acc.x * inv); u.s4[1] = f2bf(acc.y * inv);
    u.s4[2] = f2bf(acc.z * inv); u.s4[3] = f2bf(acc.w * inv);
    *(uint2*)&res[((size_t)(b * 16 + 0) * Ss + qg) * 512 + h * 64 + c4 * 4] = u.v;
}

// ---------------------------------------------------------------------------
extern "C" void kernel_launch(void* const* d_in, const int* in_sizes, int n_in,
                              void* d_out, int out_size, void* d_ws, size_t ws_size,
                              hipStream_t stream)
{
    (void)in_sizes; (void)n_in; (void)out_size; (void)ws_size;
    const float* x    = (const float*)d_in[0];
    const int*   dmsk = (const int*)  d_in[1];
    const float* Wq   = (const float*)d_in[2];
    const float* Wk   = (const float*)d_in[3];
    const float* Wv   = (const float*)d_in[4];
    const float* Wout = (const float*)d_in[5];
    const float* bout = (const float*)d_in[6];
    float* out = (float*)d_out;

    const size_t NE = (size_t)Mrows * HC;   // 9437184
    u16* q   = (u16*)d_ws;                  // [b,f,s,hc]
    u16* kk  = q   + NE;                    // [b,f,s,hc]
    u16* vT  = kk  + NE;                    // [b,f,h,c,s]
    u16* res = vT  + NE;                    // [b,f,s,hc]
    u16* Wt  = res + NE;                    // 4 x 512x512 (n-major)
    float* po = (float*)(Wt + (size_t)4 * 512 * 512);   // [9][16][576][64]
    float* pl = po + (size_t)9 * 16 * Ss * 64;          // [9][16][576]

    convert_w_kernel<<<dim3(8, 8, 4), 256, 0, stream>>>(Wq, Wk, Wv, Wout, Wt);
    qkv_kernel<<<1728, 256, 0, stream>>>(x, Wt, q, kk, vT);
    attn_kernel<<<1920, 256, 0, stream>>>(q, kk, vT, dmsk, res, po, pl);
    merge_kernel<<<576, 256, 0, stream>>>(po, pl, res);
    gemm_out_kernel<<<576, 256, 0, stream>>>(
        res, Wt + (size_t)3 * 512 * 512, bout, out);
}